// Round 6
// baseline (3996.462 us; speedup 1.0000x reference)
//
#include <hip/hip_runtime.h>
#include <cstddef>
#include <cstdint>

// ---------------------------------------------------------------------------
// LSTM layer: T=512, B=64, I=512, H=512.
// Phase 1: xW = x @ W + b  (bf16 MFMA GEMM, M=32768, K=512, N=2048)
// Phase 2: persistent recurrence, 128 WGs = 4 batch-blocks x 32 hidden-slices.
//   R6: TAGGED-WORD exchange. Each exchanged value is a 4B MALL-atomic word
//       (bf16 | version<<16) -> data is self-synchronizing. No flags, no
//       store-ACK waits, no fences. Producer: 1 coalesced 1KB publish.
//       Consumer: 32 tagged loads/thread + per-word stale retry.
// ---------------------------------------------------------------------------

#define T_STEPS 512
#define NB      64      // batch
#define HID     512
#define G4      2048    // 4*H
#define KDIM    512
#define BB      4       // batch blocks (16 rows each)
#define NSL     32      // hidden slices (16 units each)
#define BLK_DW  (NSL * 256)          // dwords per (parity,block) region = 8192
#define PAR_DW  (BB * BLK_DW)        // dwords per parity = 32768

typedef short bf16x8 __attribute__((ext_vector_type(8)));
typedef float f32x4  __attribute__((ext_vector_type(4)));

__device__ __forceinline__ float bf2f(unsigned short s) {
    unsigned u = ((unsigned)s) << 16;
    float f; __builtin_memcpy(&f, &u, 4); return f;
}
__device__ __forceinline__ unsigned short f2bf(float f) {
    unsigned u; __builtin_memcpy(&u, &f, 4);
    u = (u + 0x7FFFu + ((u >> 16) & 1u)) >> 16;
    return (unsigned short)u;
}

// ---------------- kernel 1: cast x to bf16 + zero both abuf parity regions --
__global__ void cast_x_kernel(const float* __restrict__ x,
                              unsigned short* __restrict__ o,
                              unsigned* __restrict__ abq) {
    if (blockIdx.x < 256)   // 256 blocks x 256 threads = 65536 dwords = 256 KB
        abq[blockIdx.x * 256 + threadIdx.x] = 0u;   // tag 0 = stale everywhere
    size_t i = (size_t)blockIdx.x * blockDim.x + threadIdx.x;  // one float4 each
    float4 v = ((const float4*)x)[i];
    ushort4 r;
    r.x = f2bf(v.x); r.y = f2bf(v.y); r.z = f2bf(v.z); r.w = f2bf(v.w);
    ((ushort4*)o)[i] = r;
}

// ---------------- kernel 2: transpose+cast [512][2048] f32 -> [2048][512] bf16
__global__ void transpose_cast(const float* __restrict__ src,
                               unsigned short* __restrict__ dst) {
    __shared__ float tile[64][65];
    const int n0 = blockIdx.x * 64;
    const int k0 = blockIdx.y * 64;
    const int c  = threadIdx.x & 63;
    const int r0 = threadIdx.x >> 6;
    for (int p = 0; p < 16; ++p) {
        int r = p * 4 + r0;
        tile[r][c] = src[(size_t)(k0 + r) * G4 + n0 + c];
    }
    __syncthreads();
    for (int p = 0; p < 16; ++p) {
        int r = p * 4 + r0;
        dst[(size_t)(n0 + r) * KDIM + k0 + c] = f2bf(tile[c][r]);
    }
}

// ---------------- kernel 3: bf16 MFMA GEMM: C[M][2048] = A[M][512]*Bt^T + bias
__global__ __launch_bounds__(256) void gemm_xw(
        const unsigned short* __restrict__ A,
        const unsigned short* __restrict__ Bt,
        const float* __restrict__ bias,
        unsigned short* __restrict__ C) {
    __shared__ unsigned short As[128][56];
    __shared__ unsigned short Bs[128][56];
    const int m0 = blockIdx.x * 128;
    const int n0 = blockIdx.y * 128;
    const int tid = threadIdx.x;
    const int lane = tid & 63, wave = tid >> 6;
    const int quad = lane >> 4, l16 = lane & 15;
    const int wm = (wave >> 1) * 64, wn = (wave & 1) * 64;
    f32x4 acc[4][4];
    for (int i = 0; i < 4; ++i)
        for (int j = 0; j < 4; ++j) acc[i][j] = (f32x4)0.0f;
    const int srow = tid >> 2, scol = (tid & 3) * 8;
    for (int k0 = 0; k0 < KDIM; k0 += 32) {
        __syncthreads();
        for (int p = 0; p < 2; ++p) {
            int row = p * 64 + srow;
            *(uint4*)&As[row][scol] =
                *(const uint4*)&A[(size_t)(m0 + row) * KDIM + k0 + scol];
            *(uint4*)&Bs[row][scol] =
                *(const uint4*)&Bt[(size_t)(n0 + row) * KDIM + k0 + scol];
        }
        __syncthreads();
        bf16x8 af[4], bf[4];
        for (int i = 0; i < 4; ++i)
            af[i] = *(const bf16x8*)&As[wm + i * 16 + l16][quad * 8];
        for (int j = 0; j < 4; ++j)
            bf[j] = *(const bf16x8*)&Bs[wn + j * 16 + l16][quad * 8];
        for (int i = 0; i < 4; ++i)
            for (int j = 0; j < 4; ++j)
                acc[i][j] = __builtin_amdgcn_mfma_f32_16x16x32_bf16(
                    af[i], bf[j], acc[i][j], 0, 0, 0);
    }
    for (int i = 0; i < 4; ++i)
        for (int j = 0; j < 4; ++j) {
            int col = n0 + wn + j * 16 + l16;
            float bv = bias[col];
            for (int r = 0; r < 4; ++r) {
                int row = m0 + wm + i * 16 + quad * 4 + r;
                C[(size_t)row * G4 + col] = f2bf(acc[i][j][r] + bv);
            }
        }
}

// ---------------- kernel 4: persistent recurrence (tagged-word exchange) ---
// abq dword layout: [parity][block i][slice j][d], d = b_local*16 + u_local.
// Word = bf16(value) | version<<16. Version of a_t is t+1 (a0 -> 1).
__global__ __launch_bounds__(256) void lstm_rec(
        const unsigned short* __restrict__ xW,   // [M][2048] bf16
        const unsigned short* __restrict__ Ut,   // [2048][512] bf16
        const float* __restrict__ a0,            // [64][512] f32
        float* __restrict__ out,                 // [T*64][512] f32
        unsigned* __restrict__ abq) {            // 2*4*32*256 dwords = 256 KB
    __shared__ unsigned short a_lds[16][520];    // [batch-local][k-global]
    __shared__ float gbuf[4][16][17];            // [gate][batch-local][unit]
    const int wgid  = blockIdx.x;
    const int i_blk = wgid >> 5;                 // batch block 0..3
    const int j_sl  = wgid & 31;                 // hidden slice 0..31
    const int tid   = threadIdx.x;
    const int wave  = tid >> 6;                  // gate index
    const int lane  = tid & 63;
    const int quad  = lane >> 4, l16 = lane & 15;
    const int j0 = j_sl * 16;
    const int b0 = i_blk * 16;
    const int bt = tid >> 4;                     // batch-local  0..15
    const int ut = tid & 15;                     // unit-local   0..15

    // --- register-resident B fragments (gate `wave`, units j0..j0+16) ---
    bf16x8 bq[16];
    {
        const unsigned short* urow =
            Ut + (size_t)(wave * HID + j0 + l16) * KDIM + quad * 8;
        for (int s = 0; s < 16; ++s)
            bq[s] = *(const bf16x8*)(urow + s * 32);
    }
    // --- per-thread state + init publish (version 1 -> parity 0) ---
    float aown = a0[(size_t)(b0 + bt) * HID + j0 + ut];
    __hip_atomic_store(
        &abq[(size_t)i_blk * BLK_DW + j_sl * 256 + tid],
        (unsigned)f2bf(aown) | (1u << 16),
        __ATOMIC_RELAXED, __HIP_MEMORY_SCOPE_AGENT);

    for (int t = 0; t < T_STEPS; ++t) {
        // --- prefetch xW gate addends in MFMA D-layout ---
        float xg[4];
        {
            const unsigned short* xp =
                xW + ((size_t)t * NB + b0 + quad * 4) * G4 + wave * HID + j0 + l16;
#pragma unroll
            for (int r = 0; r < 4; ++r)
                xg[r] = bf2f(xp[(size_t)r * G4]);
        }
        // --- stage a_{t-1}: 32 tagged loads, retry stale, scatter to LDS ---
        const unsigned want = (unsigned)(t + 1);
        const unsigned* src =
            abq + (size_t)(t & 1) * PAR_DW + (size_t)i_blk * BLK_DW;
        unsigned v[32];
#pragma unroll
        for (int q = 0; q < 32; ++q)
            v[q] = __hip_atomic_load(&src[q * 256 + tid], __ATOMIC_RELAXED,
                                     __HIP_MEMORY_SCOPE_AGENT);
#pragma unroll
        for (int q = 0; q < 32; ++q) {
            while ((v[q] >> 16) < want)
                v[q] = __hip_atomic_load(&src[q * 256 + tid], __ATOMIC_RELAXED,
                                         __HIP_MEMORY_SCOPE_AGENT);
            a_lds[bt][q * 16 + ut] = (unsigned short)v[q];
        }
        __syncthreads();

        // --- MFMA: M=16 (batch), N=16 (units), K=512; 2 indep chains ---
        f32x4 acc0 = (f32x4)0.0f, acc1 = (f32x4)0.0f;
#pragma unroll
        for (int s = 0; s < 16; s += 2) {
            bf16x8 af0 = *(const bf16x8*)&a_lds[l16][s * 32 + quad * 8];
            bf16x8 af1 = *(const bf16x8*)&a_lds[l16][(s + 1) * 32 + quad * 8];
            acc0 = __builtin_amdgcn_mfma_f32_16x16x32_bf16(af0, bq[s], acc0, 0, 0, 0);
            acc1 = __builtin_amdgcn_mfma_f32_16x16x32_bf16(af1, bq[s + 1], acc1, 0, 0, 0);
        }
#pragma unroll
        for (int r = 0; r < 4; ++r)
            gbuf[wave][quad * 4 + r][l16] = acc0[r] + acc1[r] + xg[r];
        __syncthreads();

        // --- gates (thread (bt,ut)) + immediate tagged publish ---
        {
            float gu = gbuf[0][bt][ut];
            float gf = gbuf[1][bt][ut];
            float go = gbuf[2][bt][ut];
            float gc = gbuf[3][bt][ut];
            float su = 1.f / (1.f + __expf(-gu));
            float sf = 1.f / (1.f + __expf(-gf));
            float so = 1.f / (1.f + __expf(-go));
            float e2 = __expf(2.f * gc);
            float tc = 1.f - 2.f / (e2 + 1.f);            // tanh(gc)
            float cc = su * tc + sf * aown;                // forget * a_{t-1}
            float ec = __expf(2.f * cc);
            float th = 1.f - 2.f / (ec + 1.f);             // tanh(c)
            float a  = so * th;
            aown = a;
            // publish FIRST (critical path), out-store after (fire & forget)
            __hip_atomic_store(
                &abq[(size_t)((t + 1) & 1) * PAR_DW + (size_t)i_blk * BLK_DW +
                     j_sl * 256 + tid],
                (unsigned)f2bf(a) | ((unsigned)(t + 2) << 16),
                __ATOMIC_RELAXED, __HIP_MEMORY_SCOPE_AGENT);
            out[((size_t)t * NB + b0 + bt) * HID + j0 + ut] = a;
        }
        // no trailing barrier: next stage's syncthreads separates a_lds reuse
    }
}

// ---------------------------------------------------------------------------
extern "C" void kernel_launch(void* const* d_in, const int* in_sizes, int n_in,
                              void* d_out, int out_size, void* d_ws, size_t ws_size,
                              hipStream_t stream) {
    (void)in_sizes; (void)n_in; (void)out_size; (void)ws_size;
    const float* x    = (const float*)d_in[0];   // [T,B,I]
    const float* a0   = (const float*)d_in[1];   // [B,H]
    const float* W    = (const float*)d_in[2];   // [I,4H]
    const float* U    = (const float*)d_in[3];   // [H,4H]
    const float* bias = (const float*)d_in[4];   // [4H]
    float* out = (float*)d_out;

    char* ws = (char*)d_ws;
    unsigned short* xbf  = (unsigned short*)(ws);                 // 33,554,432 B
    unsigned short* Wt   = (unsigned short*)(ws + 33554432);      //  2,097,152 B
    unsigned short* Ut   = (unsigned short*)(ws + 35651584);      //  2,097,152 B
    unsigned short* xWp  = (unsigned short*)(ws + 37748736);      // 134,217,728 B
    unsigned*       abq  = (unsigned*)(ws + 171966464);           //    262,144 B

    cast_x_kernel<<<16384, 256, 0, stream>>>(x, xbf, abq);
    transpose_cast<<<dim3(32, 8), 256, 0, stream>>>(W, Wt);
    transpose_cast<<<dim3(32, 8), 256, 0, stream>>>(U, Ut);
    gemm_xw<<<dim3(256, 16), 256, 0, stream>>>(xbf, Wt, bias, xWp);
    lstm_rec<<<BB * NSL, 256, 0, stream>>>(xWp, Ut, a0, out, abq);
}

// Round 7
// 2167.590 us; speedup vs baseline: 1.8437x; 1.8437x over previous
//
#include <hip/hip_runtime.h>
#include <cstddef>
#include <cstdint>

// ---------------------------------------------------------------------------
// LSTM layer: T=512, B=64, I=512, H=512.
// Phase 1: xW = x @ W + b  (bf16 MFMA GEMM, M=32768, K=512, N=2048)
// Phase 2: persistent recurrence, 128 WGs = 4 batch-blocks x 32 hidden-slices.
//   R7: tagged-word exchange with BATCHED retry (R6 retried 32 words
//       serially -> 32 round trips; now 8x16B chunks retried in parallel
//       rounds of ~1 round trip each). Fire-and-forget publish (no ACK).
// ---------------------------------------------------------------------------

#define T_STEPS 512
#define NB      64      // batch
#define HID     512
#define G4      2048    // 4*H
#define KDIM    512
#define BB      4       // batch blocks (16 rows each)
#define NSL     32      // hidden slices (16 units each)
#define BLK_DW  (NSL * 256)          // dwords per (parity,block) region = 8192
#define PAR_DW  (BB * BLK_DW)        // dwords per parity = 32768

typedef short bf16x8 __attribute__((ext_vector_type(8)));
typedef float f32x4  __attribute__((ext_vector_type(4)));

__device__ __forceinline__ float bf2f(unsigned short s) {
    unsigned u = ((unsigned)s) << 16;
    float f; __builtin_memcpy(&f, &u, 4); return f;
}
__device__ __forceinline__ unsigned short f2bf(float f) {
    unsigned u; __builtin_memcpy(&u, &f, 4);
    u = (u + 0x7FFFu + ((u >> 16) & 1u)) >> 16;
    return (unsigned short)u;
}

// ---------------- kernel 1: cast x to bf16 + zero both abuf parity regions --
__global__ void cast_x_kernel(const float* __restrict__ x,
                              unsigned short* __restrict__ o,
                              unsigned* __restrict__ abq) {
    if (blockIdx.x < 256)   // 256 x 256 = 65536 dwords = 256 KB
        abq[blockIdx.x * 256 + threadIdx.x] = 0u;   // tag 0 = stale
    size_t i = (size_t)blockIdx.x * blockDim.x + threadIdx.x;  // one float4 each
    float4 v = ((const float4*)x)[i];
    ushort4 r;
    r.x = f2bf(v.x); r.y = f2bf(v.y); r.z = f2bf(v.z); r.w = f2bf(v.w);
    ((ushort4*)o)[i] = r;
}

// ---------------- kernel 2: transpose+cast [512][2048] f32 -> [2048][512] bf16
__global__ void transpose_cast(const float* __restrict__ src,
                               unsigned short* __restrict__ dst) {
    __shared__ float tile[64][65];
    const int n0 = blockIdx.x * 64;
    const int k0 = blockIdx.y * 64;
    const int c  = threadIdx.x & 63;
    const int r0 = threadIdx.x >> 6;
    for (int p = 0; p < 16; ++p) {
        int r = p * 4 + r0;
        tile[r][c] = src[(size_t)(k0 + r) * G4 + n0 + c];
    }
    __syncthreads();
    for (int p = 0; p < 16; ++p) {
        int r = p * 4 + r0;
        dst[(size_t)(n0 + r) * KDIM + k0 + c] = f2bf(tile[c][r]);
    }
}

// ---------------- kernel 3: bf16 MFMA GEMM: C[M][2048] = A[M][512]*Bt^T + bias
__global__ __launch_bounds__(256) void gemm_xw(
        const unsigned short* __restrict__ A,
        const unsigned short* __restrict__ Bt,
        const float* __restrict__ bias,
        unsigned short* __restrict__ C) {
    __shared__ unsigned short As[128][56];
    __shared__ unsigned short Bs[128][56];
    const int m0 = blockIdx.x * 128;
    const int n0 = blockIdx.y * 128;
    const int tid = threadIdx.x;
    const int lane = tid & 63, wave = tid >> 6;
    const int quad = lane >> 4, l16 = lane & 15;
    const int wm = (wave >> 1) * 64, wn = (wave & 1) * 64;
    f32x4 acc[4][4];
    for (int i = 0; i < 4; ++i)
        for (int j = 0; j < 4; ++j) acc[i][j] = (f32x4)0.0f;
    const int srow = tid >> 2, scol = (tid & 3) * 8;
    for (int k0 = 0; k0 < KDIM; k0 += 32) {
        __syncthreads();
        for (int p = 0; p < 2; ++p) {
            int row = p * 64 + srow;
            *(uint4*)&As[row][scol] =
                *(const uint4*)&A[(size_t)(m0 + row) * KDIM + k0 + scol];
            *(uint4*)&Bs[row][scol] =
                *(const uint4*)&Bt[(size_t)(n0 + row) * KDIM + k0 + scol];
        }
        __syncthreads();
        bf16x8 af[4], bf[4];
        for (int i = 0; i < 4; ++i)
            af[i] = *(const bf16x8*)&As[wm + i * 16 + l16][quad * 8];
        for (int j = 0; j < 4; ++j)
            bf[j] = *(const bf16x8*)&Bs[wn + j * 16 + l16][quad * 8];
        for (int i = 0; i < 4; ++i)
            for (int j = 0; j < 4; ++j)
                acc[i][j] = __builtin_amdgcn_mfma_f32_16x16x32_bf16(
                    af[i], bf[j], acc[i][j], 0, 0, 0);
    }
    for (int i = 0; i < 4; ++i)
        for (int j = 0; j < 4; ++j) {
            int col = n0 + wn + j * 16 + l16;
            float bv = bias[col];
            for (int r = 0; r < 4; ++r) {
                int row = m0 + wm + i * 16 + quad * 4 + r;
                C[(size_t)row * G4 + col] = f2bf(acc[i][j][r] + bv);
            }
        }
}

// ---------------- kernel 4: persistent recurrence (tagged, batched retry) --
// abq dword layout: [parity][block i][slice j][d], d = b_local*16 + u_local.
// Word = bf16(value) | version<<16. Version of a_t is t+1 (a0 -> 1).
__global__ __launch_bounds__(256) void lstm_rec(
        const unsigned short* __restrict__ xW,   // [M][2048] bf16
        const unsigned short* __restrict__ Ut,   // [2048][512] bf16
        const float* __restrict__ a0,            // [64][512] f32
        float* __restrict__ out,                 // [T*64][512] f32
        unsigned* __restrict__ abq) {            // 2*4*32*256 dwords = 256 KB
    __shared__ unsigned short a_lds[16][520];    // [batch-local][k-global]
    __shared__ float gbuf[4][16][17];            // [gate][batch-local][unit]
    const int wgid  = blockIdx.x;
    const int i_blk = wgid >> 5;                 // batch block 0..3
    const int j_sl  = wgid & 31;                 // hidden slice 0..31
    const int tid   = threadIdx.x;
    const int wave  = tid >> 6;                  // gate index
    const int lane  = tid & 63;
    const int quad  = lane >> 4, l16 = lane & 15;
    const int j0 = j_sl * 16;
    const int b0 = i_blk * 16;
    const int bt = tid >> 4;                     // batch-local  0..15
    const int ut = tid & 15;                     // unit-local   0..15

    // --- register-resident B fragments (gate `wave`, units j0..j0+16) ---
    bf16x8 bq[16];
    {
        const unsigned short* urow =
            Ut + (size_t)(wave * HID + j0 + l16) * KDIM + quad * 8;
        for (int s = 0; s < 16; ++s)
            bq[s] = *(const bf16x8*)(urow + s * 32);
    }
    // --- per-thread state + init publish (version 1 -> parity 0) ---
    float aown = a0[(size_t)(b0 + bt) * HID + j0 + ut];
    __hip_atomic_store(
        &abq[(size_t)i_blk * BLK_DW + j_sl * 256 + tid],
        (unsigned)f2bf(aown) | (1u << 16),
        __ATOMIC_RELAXED, __HIP_MEMORY_SCOPE_AGENT);

    for (int t = 0; t < T_STEPS; ++t) {
        // --- prefetch xW gate addends in MFMA D-layout ---
        float xg[4];
        {
            const unsigned short* xp =
                xW + ((size_t)t * NB + b0 + quad * 4) * G4 + wave * HID + j0 + l16;
#pragma unroll
            for (int r = 0; r < 4; ++r)
                xg[r] = bf2f(xp[(size_t)r * G4]);
        }
        // --- stage a_{t-1}: 8 chunks x 4 tagged dwords, BATCHED retry ---
        // chunk c = q*256+tid: dwords 4c..4c+3; sl=c>>6, bt'=(c>>2)&15, u4=c&3
        const unsigned want = (unsigned)(t + 1);
        const unsigned* src =
            abq + (size_t)(t & 1) * PAR_DW + (size_t)i_blk * BLK_DW;
        unsigned v[32];
#pragma unroll
        for (int q = 0; q < 8; ++q) {
            const unsigned* p = src + (size_t)(q * 256 + tid) * 4;
#pragma unroll
            for (int d = 0; d < 4; ++d)
                v[q * 4 + d] = __hip_atomic_load(p + d, __ATOMIC_RELAXED,
                                                 __HIP_MEMORY_SCOPE_AGENT);
        }
        unsigned stale = 0;
#pragma unroll
        for (int q = 0; q < 8; ++q) {
            bool ok = (v[q * 4 + 0] >> 16) >= want &&
                      (v[q * 4 + 1] >> 16) >= want &&
                      (v[q * 4 + 2] >> 16) >= want &&
                      (v[q * 4 + 3] >> 16) >= want;
            if (!ok) stale |= 1u << q;
        }
        while (stale) {                        // each round ~1 MALL round trip
#pragma unroll
            for (int q = 0; q < 8; ++q)
                if (stale & (1u << q)) {
                    const unsigned* p = src + (size_t)(q * 256 + tid) * 4;
#pragma unroll
                    for (int d = 0; d < 4; ++d)
                        v[q * 4 + d] = __hip_atomic_load(
                            p + d, __ATOMIC_RELAXED, __HIP_MEMORY_SCOPE_AGENT);
                }
            unsigned ns = 0;
#pragma unroll
            for (int q = 0; q < 8; ++q)
                if (stale & (1u << q)) {
                    bool ok = (v[q * 4 + 0] >> 16) >= want &&
                              (v[q * 4 + 1] >> 16) >= want &&
                              (v[q * 4 + 2] >> 16) >= want &&
                              (v[q * 4 + 3] >> 16) >= want;
                    if (!ok) ns |= 1u << q;
                }
            stale = ns;
        }
        // scatter to LDS: 8B packed writes (2-way banks = free)
#pragma unroll
        for (int q = 0; q < 8; ++q) {
            int c = q * 256 + tid;
            union { unsigned long long w; unsigned short s[4]; } pk;
            pk.s[0] = (unsigned short)v[q * 4 + 0];
            pk.s[1] = (unsigned short)v[q * 4 + 1];
            pk.s[2] = (unsigned short)v[q * 4 + 2];
            pk.s[3] = (unsigned short)v[q * 4 + 3];
            *(unsigned long long*)
                &a_lds[(c >> 2) & 15][(c >> 6) * 16 + (c & 3) * 4] = pk.w;
        }
        __syncthreads();

        // --- MFMA: M=16 (batch), N=16 (units), K=512; 4 indep chains ---
        f32x4 acc0 = (f32x4)0.0f, acc1 = (f32x4)0.0f;
        f32x4 acc2 = (f32x4)0.0f, acc3 = (f32x4)0.0f;
#pragma unroll
        for (int s = 0; s < 16; s += 4) {
            bf16x8 af0 = *(const bf16x8*)&a_lds[l16][(s + 0) * 32 + quad * 8];
            bf16x8 af1 = *(const bf16x8*)&a_lds[l16][(s + 1) * 32 + quad * 8];
            bf16x8 af2 = *(const bf16x8*)&a_lds[l16][(s + 2) * 32 + quad * 8];
            bf16x8 af3 = *(const bf16x8*)&a_lds[l16][(s + 3) * 32 + quad * 8];
            acc0 = __builtin_amdgcn_mfma_f32_16x16x32_bf16(af0, bq[s + 0], acc0, 0, 0, 0);
            acc1 = __builtin_amdgcn_mfma_f32_16x16x32_bf16(af1, bq[s + 1], acc1, 0, 0, 0);
            acc2 = __builtin_amdgcn_mfma_f32_16x16x32_bf16(af2, bq[s + 2], acc2, 0, 0, 0);
            acc3 = __builtin_amdgcn_mfma_f32_16x16x32_bf16(af3, bq[s + 3], acc3, 0, 0, 0);
        }
#pragma unroll
        for (int r = 0; r < 4; ++r)
            gbuf[wave][quad * 4 + r][l16] =
                (acc0[r] + acc1[r]) + (acc2[r] + acc3[r]) + xg[r];
        __syncthreads();

        // --- gates (thread (bt,ut)); publish FIRST, out-store after ---
        {
            float gu = gbuf[0][bt][ut];
            float gf = gbuf[1][bt][ut];
            float go = gbuf[2][bt][ut];
            float gc = gbuf[3][bt][ut];
            float su = 1.f / (1.f + __expf(-gu));
            float sf = 1.f / (1.f + __expf(-gf));
            float so = 1.f / (1.f + __expf(-go));
            float e2 = __expf(2.f * gc);
            float tc = 1.f - 2.f / (e2 + 1.f);            // tanh(gc)
            float cc = su * tc + sf * aown;                // forget * a_{t-1}
            float ec = __expf(2.f * cc);
            float th = 1.f - 2.f / (ec + 1.f);             // tanh(c)
            float a  = so * th;
            aown = a;
            __hip_atomic_store(
                &abq[(size_t)((t + 1) & 1) * PAR_DW + (size_t)i_blk * BLK_DW +
                     j_sl * 256 + tid],
                (unsigned)f2bf(a) | ((unsigned)(t + 2) << 16),
                __ATOMIC_RELAXED, __HIP_MEMORY_SCOPE_AGENT);
            out[((size_t)t * NB + b0 + bt) * HID + j0 + ut] = a;
        }
        // next iteration's first __syncthreads separates a_lds reuse
    }
}

// ---------------------------------------------------------------------------
extern "C" void kernel_launch(void* const* d_in, const int* in_sizes, int n_in,
                              void* d_out, int out_size, void* d_ws, size_t ws_size,
                              hipStream_t stream) {
    (void)in_sizes; (void)n_in; (void)out_size; (void)ws_size;
    const float* x    = (const float*)d_in[0];   // [T,B,I]
    const float* a0   = (const float*)d_in[1];   // [B,H]
    const float* W    = (const float*)d_in[2];   // [I,4H]
    const float* U    = (const float*)d_in[3];   // [H,4H]
    const float* bias = (const float*)d_in[4];   // [4H]
    float* out = (float*)d_out;

    char* ws = (char*)d_ws;
    unsigned short* xbf  = (unsigned short*)(ws);                 // 33,554,432 B
    unsigned short* Wt   = (unsigned short*)(ws + 33554432);      //  2,097,152 B
    unsigned short* Ut   = (unsigned short*)(ws + 35651584);      //  2,097,152 B
    unsigned short* xWp  = (unsigned short*)(ws + 37748736);      // 134,217,728 B
    unsigned*       abq  = (unsigned*)(ws + 171966464);           //    262,144 B

    cast_x_kernel<<<16384, 256, 0, stream>>>(x, xbf, abq);
    transpose_cast<<<dim3(32, 8), 256, 0, stream>>>(W, Wt);
    transpose_cast<<<dim3(32, 8), 256, 0, stream>>>(U, Ut);
    gemm_xw<<<dim3(256, 16), 256, 0, stream>>>(xbf, Wt, bias, xWp);
    lstm_rec<<<BB * NSL, 256, 0, stream>>>(xWp, Ut, a0, out, abq);
}

// Round 8
// 1304.643 us; speedup vs baseline: 3.0633x; 1.6614x over previous
//
#include <hip/hip_runtime.h>
#include <cstddef>
#include <cstdint>

// ---------------------------------------------------------------------------
// LSTM layer: T=512, B=64, I=512, H=512.
// Phase 1: xW = x @ W + b  (bf16 MFMA GEMM), epilogue writes xWp in
//          per-WG-per-step contiguous layout [t][blk][slice][gate][256].
// Phase 2: persistent recurrence, 128 WGs = 4 batch-blocks x 32 hidden-slices.
//   R8: tagged-word exchange with coalesced dwordx4 sc1 staging (inline asm,
//       8 chunks + waitcnt in one block), uniform full-reload retry.
// ---------------------------------------------------------------------------

#define T_STEPS 512
#define NB      64      // batch
#define HID     512
#define G4      2048    // 4*H
#define KDIM    512
#define BB      4       // batch blocks (16 rows each)
#define NSL     32      // hidden slices (16 units each)
#define BLK_DW  (NSL * 256)          // dwords per (parity,block) region = 8192
#define PAR_DW  (BB * BLK_DW)        // dwords per parity = 32768

typedef short bf16x8 __attribute__((ext_vector_type(8)));
typedef float f32x4  __attribute__((ext_vector_type(4)));
typedef unsigned int u32x4 __attribute__((ext_vector_type(4)));

__device__ __forceinline__ float bf2f(unsigned short s) {
    unsigned u = ((unsigned)s) << 16;
    float f; __builtin_memcpy(&f, &u, 4); return f;
}
__device__ __forceinline__ unsigned short f2bf(float f) {
    unsigned u; __builtin_memcpy(&u, &f, 4);
    u = (u + 0x7FFFu + ((u >> 16) & 1u)) >> 16;
    return (unsigned short)u;
}
__device__ __forceinline__ unsigned min4(u32x4 v) {
    unsigned a = v[0] < v[1] ? v[0] : v[1];
    unsigned b = v[2] < v[3] ? v[2] : v[3];
    return a < b ? a : b;
}

// ---------------- kernel 1: cast x to bf16 + zero both abq parity regions --
__global__ void cast_x_kernel(const float* __restrict__ x,
                              unsigned short* __restrict__ o,
                              unsigned* __restrict__ abq) {
    if (blockIdx.x < 256)   // 256 x 256 = 65536 dwords = 256 KB
        abq[blockIdx.x * 256 + threadIdx.x] = 0u;   // tag 0 = stale
    size_t i = (size_t)blockIdx.x * blockDim.x + threadIdx.x;  // one float4 each
    float4 v = ((const float4*)x)[i];
    ushort4 r;
    r.x = f2bf(v.x); r.y = f2bf(v.y); r.z = f2bf(v.z); r.w = f2bf(v.w);
    ((ushort4*)o)[i] = r;
}

// ---------------- kernel 2: transpose+cast [512][2048] f32 -> [2048][512] bf16
__global__ void transpose_cast(const float* __restrict__ src,
                               unsigned short* __restrict__ dst) {
    __shared__ float tile[64][65];
    const int n0 = blockIdx.x * 64;
    const int k0 = blockIdx.y * 64;
    const int c  = threadIdx.x & 63;
    const int r0 = threadIdx.x >> 6;
    for (int p = 0; p < 16; ++p) {
        int r = p * 4 + r0;
        tile[r][c] = src[(size_t)(k0 + r) * G4 + n0 + c];
    }
    __syncthreads();
    for (int p = 0; p < 16; ++p) {
        int r = p * 4 + r0;
        dst[(size_t)(n0 + r) * KDIM + k0 + c] = f2bf(tile[c][r]);
    }
}

// ---------------- kernel 3: bf16 MFMA GEMM, recurrence-layout epilogue ------
// C layout: [t][blk][slice][gate][bt*16+ut] bf16 (contiguous 2 KB per WG-step)
__global__ __launch_bounds__(256) void gemm_xw(
        const unsigned short* __restrict__ A,
        const unsigned short* __restrict__ Bt,
        const float* __restrict__ bias,
        unsigned short* __restrict__ C) {
    __shared__ unsigned short As[128][56];
    __shared__ unsigned short Bs[128][56];
    const int m0 = blockIdx.x * 128;
    const int n0 = blockIdx.y * 128;
    const int tid = threadIdx.x;
    const int lane = tid & 63, wave = tid >> 6;
    const int quad = lane >> 4, l16 = lane & 15;
    const int wm = (wave >> 1) * 64, wn = (wave & 1) * 64;
    f32x4 acc[4][4];
    for (int i = 0; i < 4; ++i)
        for (int j = 0; j < 4; ++j) acc[i][j] = (f32x4)0.0f;
    const int srow = tid >> 2, scol = (tid & 3) * 8;
    for (int k0 = 0; k0 < KDIM; k0 += 32) {
        __syncthreads();
        for (int p = 0; p < 2; ++p) {
            int row = p * 64 + srow;
            *(uint4*)&As[row][scol] =
                *(const uint4*)&A[(size_t)(m0 + row) * KDIM + k0 + scol];
            *(uint4*)&Bs[row][scol] =
                *(const uint4*)&Bt[(size_t)(n0 + row) * KDIM + k0 + scol];
        }
        __syncthreads();
        bf16x8 af[4], bf[4];
        for (int i = 0; i < 4; ++i)
            af[i] = *(const bf16x8*)&As[wm + i * 16 + l16][quad * 8];
        for (int j = 0; j < 4; ++j)
            bf[j] = *(const bf16x8*)&Bs[wn + j * 16 + l16][quad * 8];
        for (int i = 0; i < 4; ++i)
            for (int j = 0; j < 4; ++j)
                acc[i][j] = __builtin_amdgcn_mfma_f32_16x16x32_bf16(
                    af[i], bf[j], acc[i][j], 0, 0, 0);
    }
    for (int i = 0; i < 4; ++i)
        for (int j = 0; j < 4; ++j) {
            int col = n0 + wn + j * 16 + l16;          // 0..2047
            int g   = col >> 9;                        // gate
            int u   = col & 511;                       // hidden unit
            int js  = u >> 4, ut = u & 15;
            float bv = bias[col];
            for (int r = 0; r < 4; ++r) {
                int row = m0 + wm + i * 16 + quad * 4 + r;   // t*64 + b
                int t = row >> 6, b = row & 63;
                size_t off = ((((size_t)t * BB + (b >> 4)) * NSL + js) * 4 + g)
                                 * 256 + (b & 15) * 16 + ut;
                C[off] = f2bf(acc[i][j][r] + bv);
            }
        }
}

// ---------------- kernel 4: persistent recurrence (tagged dwordx4 sc1) -----
// abq dword layout: [parity][block i][slice j][d], d = b_local*16 + u_local.
// Word = bf16(value) | version<<16. Version of a_t is t+1 (a0 -> 1).
__global__ __launch_bounds__(256) void lstm_rec(
        const unsigned short* __restrict__ xWp,  // [t][blk][slice][4][256] bf16
        const unsigned short* __restrict__ Ut,   // [2048][512] bf16
        const float* __restrict__ a0,            // [64][512] f32
        float* __restrict__ out,                 // [T*64][512] f32
        unsigned* __restrict__ abq) {            // 2*4*32*256 dwords = 256 KB
    __shared__ unsigned short a_lds[16][520];    // [batch-local][k-global]
    __shared__ float gbuf[4][16][17];            // [gate][batch-local][unit]
    const int wgid  = blockIdx.x;
    const int i_blk = wgid >> 5;                 // batch block 0..3
    const int j_sl  = wgid & 31;                 // hidden slice 0..31
    const int tid   = threadIdx.x;
    const int wave  = tid >> 6;                  // gate index
    const int lane  = tid & 63;
    const int quad  = lane >> 4, l16 = lane & 15;
    const int j0 = j_sl * 16;
    const int b0 = i_blk * 16;
    const int bt = tid >> 4;                     // batch-local  0..15
    const int ut = tid & 15;                     // unit-local   0..15

    // --- register-resident B fragments (gate `wave`, units j0..j0+16) ---
    bf16x8 bq[16];
    {
        const unsigned short* urow =
            Ut + (size_t)(wave * HID + j0 + l16) * KDIM + quad * 8;
        for (int s = 0; s < 16; ++s)
            bq[s] = *(const bf16x8*)(urow + s * 32);
    }
    // --- per-thread state + init publish (version 1 -> parity 0) ---
    float aown = a0[(size_t)(b0 + bt) * HID + j0 + ut];
    __hip_atomic_store(
        &abq[(size_t)i_blk * BLK_DW + j_sl * 256 + tid],
        (unsigned)f2bf(aown) | (1u << 16),
        __ATOMIC_RELAXED, __HIP_MEMORY_SCOPE_AGENT);

    for (int t = 0; t < T_STEPS; ++t) {
        // --- prefetch xW gate addends (contiguous 2 KB block, dense) ---
        unsigned short xs[4];
        {
            const unsigned short* xp =
                xWp + (((size_t)t * BB + i_blk) * NSL + j_sl) * 1024;
#pragma unroll
            for (int w = 0; w < 4; ++w)
                xs[w] = xp[w * 256 + tid];
        }
        // --- stage a_{t-1}: 8 tagged 16B chunks, coalesced dwordx4 sc1,
        //     uniform full-reload retry (each round ~1 MALL round trip) ---
        const unsigned* srcblk =
            abq + (size_t)(t & 1) * PAR_DW + (size_t)i_blk * BLK_DW;
        const u32x4* pc = (const u32x4*)srcblk + tid;
        const unsigned w16 = (unsigned)(t + 1) << 16;
        u32x4 d0, d1, d2, d3, d4, d5, d6, d7;
        bool ok;
        do {
            asm volatile(
                "global_load_dwordx4 %0, %8, off sc1\n\t"
                "global_load_dwordx4 %1, %9, off sc1\n\t"
                "global_load_dwordx4 %2, %10, off sc1\n\t"
                "global_load_dwordx4 %3, %11, off sc1\n\t"
                "global_load_dwordx4 %4, %12, off sc1\n\t"
                "global_load_dwordx4 %5, %13, off sc1\n\t"
                "global_load_dwordx4 %6, %14, off sc1\n\t"
                "global_load_dwordx4 %7, %15, off sc1\n\t"
                "s_waitcnt vmcnt(0)"
                : "=&v"(d0), "=&v"(d1), "=&v"(d2), "=&v"(d3),
                  "=&v"(d4), "=&v"(d5), "=&v"(d6), "=&v"(d7)
                : "v"(pc),        "v"(pc + 256),  "v"(pc + 512),
                  "v"(pc + 768),  "v"(pc + 1024), "v"(pc + 1280),
                  "v"(pc + 1536), "v"(pc + 1792)
                : "memory");
            unsigned m01 = min4(d0) < min4(d1) ? min4(d0) : min4(d1);
            unsigned m23 = min4(d2) < min4(d3) ? min4(d2) : min4(d3);
            unsigned m45 = min4(d4) < min4(d5) ? min4(d4) : min4(d5);
            unsigned m67 = min4(d6) < min4(d7) ? min4(d6) : min4(d7);
            unsigned ma = m01 < m23 ? m01 : m23;
            unsigned mb = m45 < m67 ? m45 : m67;
            ok = ((ma < mb ? ma : mb) >= w16);
        } while (!ok);
        // scatter to LDS: strip tags, 8B packed writes
#define SCAT(q, d)                                                          \
        {                                                                   \
            int c = (q) * 256 + tid;                                        \
            unsigned lo = ((d)[0] & 0xffffu) | ((d)[1] << 16);              \
            unsigned hi = ((d)[2] & 0xffffu) | ((d)[3] << 16);              \
            uint2 pk; pk.x = lo; pk.y = hi;                                 \
            *(uint2*)&a_lds[(c >> 2) & 15][(c >> 6) * 16 + (c & 3) * 4] = pk;\
        }
        SCAT(0, d0) SCAT(1, d1) SCAT(2, d2) SCAT(3, d3)
        SCAT(4, d4) SCAT(5, d5) SCAT(6, d6) SCAT(7, d7)
#undef SCAT
        __syncthreads();

        // --- MFMA: M=16 (batch), N=16 (units), K=512; 4 indep chains ---
        f32x4 acc0 = (f32x4)0.0f, acc1 = (f32x4)0.0f;
        f32x4 acc2 = (f32x4)0.0f, acc3 = (f32x4)0.0f;
#pragma unroll
        for (int s = 0; s < 16; s += 4) {
            bf16x8 af0 = *(const bf16x8*)&a_lds[l16][(s + 0) * 32 + quad * 8];
            bf16x8 af1 = *(const bf16x8*)&a_lds[l16][(s + 1) * 32 + quad * 8];
            bf16x8 af2 = *(const bf16x8*)&a_lds[l16][(s + 2) * 32 + quad * 8];
            bf16x8 af3 = *(const bf16x8*)&a_lds[l16][(s + 3) * 32 + quad * 8];
            acc0 = __builtin_amdgcn_mfma_f32_16x16x32_bf16(af0, bq[s + 0], acc0, 0, 0, 0);
            acc1 = __builtin_amdgcn_mfma_f32_16x16x32_bf16(af1, bq[s + 1], acc1, 0, 0, 0);
            acc2 = __builtin_amdgcn_mfma_f32_16x16x32_bf16(af2, bq[s + 2], acc2, 0, 0, 0);
            acc3 = __builtin_amdgcn_mfma_f32_16x16x32_bf16(af3, bq[s + 3], acc3, 0, 0, 0);
        }
#pragma unroll
        for (int r = 0; r < 4; ++r)
            gbuf[wave][quad * 4 + r][l16] =
                (acc0[r] + acc1[r]) + (acc2[r] + acc3[r]);
        __syncthreads();

        // --- gates (thread (bt,ut)); publish FIRST, out-store after ---
        {
            float gu = gbuf[0][bt][ut] + bf2f(xs[0]);
            float gf = gbuf[1][bt][ut] + bf2f(xs[1]);
            float go = gbuf[2][bt][ut] + bf2f(xs[2]);
            float gc = gbuf[3][bt][ut] + bf2f(xs[3]);
            float su = 1.f / (1.f + __expf(-gu));
            float sf = 1.f / (1.f + __expf(-gf));
            float so = 1.f / (1.f + __expf(-go));
            float e2 = __expf(2.f * gc);
            float tc = 1.f - 2.f / (e2 + 1.f);            // tanh(gc)
            float cc = su * tc + sf * aown;                // forget * a_{t-1}
            float ec = __expf(2.f * cc);
            float th = 1.f - 2.f / (ec + 1.f);             // tanh(c)
            float a  = so * th;
            aown = a;
            __hip_atomic_store(
                &abq[(size_t)((t + 1) & 1) * PAR_DW + (size_t)i_blk * BLK_DW +
                     j_sl * 256 + tid],
                (unsigned)f2bf(a) | ((unsigned)(t + 2) << 16),
                __ATOMIC_RELAXED, __HIP_MEMORY_SCOPE_AGENT);
            out[((size_t)t * NB + b0 + bt) * HID + j0 + ut] = a;
        }
        // next iteration's first __syncthreads separates a_lds reuse
    }
}

// ---------------------------------------------------------------------------
extern "C" void kernel_launch(void* const* d_in, const int* in_sizes, int n_in,
                              void* d_out, int out_size, void* d_ws, size_t ws_size,
                              hipStream_t stream) {
    (void)in_sizes; (void)n_in; (void)out_size; (void)ws_size;
    const float* x    = (const float*)d_in[0];   // [T,B,I]
    const float* a0   = (const float*)d_in[1];   // [B,H]
    const float* W    = (const float*)d_in[2];   // [I,4H]
    const float* U    = (const float*)d_in[3];   // [H,4H]
    const float* bias = (const float*)d_in[4];   // [4H]
    float* out = (float*)d_out;

    char* ws = (char*)d_ws;
    unsigned short* xbf  = (unsigned short*)(ws);                 // 33,554,432 B
    unsigned short* Wt   = (unsigned short*)(ws + 33554432);      //  2,097,152 B
    unsigned short* Ut   = (unsigned short*)(ws + 35651584);      //  2,097,152 B
    unsigned short* xWp  = (unsigned short*)(ws + 37748736);      // 134,217,728 B
    unsigned*       abq  = (unsigned*)(ws + 171966464);           //    262,144 B

    cast_x_kernel<<<16384, 256, 0, stream>>>(x, xbf, abq);
    transpose_cast<<<dim3(32, 8), 256, 0, stream>>>(W, Wt);
    transpose_cast<<<dim3(32, 8), 256, 0, stream>>>(U, Ut);
    gemm_xw<<<dim3(256, 16), 256, 0, stream>>>(xbf, Wt, bias, xWp);
    lstm_rec<<<BB * NSL, 256, 0, stream>>>(xWp, Ut, a0, out, abq);
}